// Round 11
// baseline (67.569 us; speedup 1.0000x reference)
//
#include <hip/hip_runtime.h>

// ---------------------------------------------------------------------------
// Fused MLP-embedding cosine-similarity kernel for MI355X (gfx950).
//   e = (x @ W1^T + b1 -> selu) @ W2^T + b2 -> selu) @ W3^T + b3
//   out = sigmoid((cos(e1,e2)+1)/2)
// Round 11: r8 structure (58.8us; once-per-block weight loads, 2 tiles x
// 4 stripes per wave) + cross-phase WEIGHT PREFETCH: issue phase N+1's
// global weight loads before phase N's compute so L2 latency (~200-500cy)
// hides under MFMA/LDS work. r10 taught that weight loads inside inner
// k-passes stall unhidden (66.9us); r8's stall was the same latency at
// phase starts. Peak live ~140 VGPR -> __launch_bounds__(512,3) (cap 170,
// 12 waves/CU). Everything else identical to r8.
// ---------------------------------------------------------------------------

typedef __bf16 bf16x8 __attribute__((ext_vector_type(8)));
typedef __bf16 bf16x4 __attribute__((ext_vector_type(4)));
typedef float  f32x4  __attribute__((ext_vector_type(4)));

constexpr int WS_W1 = 0;       // 16 tiles * 4 ks * 512 bf16
constexpr int WS_W2 = 32768;   // 16 tiles * 8 ks * 512
constexpr int WS_W3 = 98304;   //  8 tiles * 8 ks * 512

__device__ __forceinline__ float selu_f(float x) {
    const float scale = 1.0507009873554805f;
    const float sa    = 1.7580993408473766f;   // scale * alpha
    float xp = fmaxf(x, 0.f);
    float xn = fminf(x, 0.f);
    return fmaf(scale, xp, sa * (__expf(xn) - 1.f));
}

// activation fragment (B-operand): lane holds X[row][kcol .. kcol+7]
__device__ __forceinline__ bf16x8 read_act(const __bf16* lds, int row, int kcol) {
    unsigned byte = (unsigned)((row * 128 + kcol) * 2) ^ ((unsigned)(row & 7) << 4);
    return *(const bf16x8*)((const char*)lds + byte);
}

// store one D fragment: 4 consecutive neurons (col0..col0+3) at sample row
template<bool SELU>
__device__ __forceinline__ void store_act(__bf16* lds, int row, int col0, f32x4 a) {
    float v0 = a[0], v1 = a[1], v2 = a[2], v3 = a[3];
    if (SELU) { v0 = selu_f(v0); v1 = selu_f(v1); v2 = selu_f(v2); v3 = selu_f(v3); }
    bf16x4 u;
    u[0] = (__bf16)v0; u[1] = (__bf16)v1; u[2] = (__bf16)v2; u[3] = (__bf16)v3;
    unsigned byte = (unsigned)((row * 128 + col0) * 2) ^ ((unsigned)(row & 7) << 4);
    *(bf16x4*)((char*)lds + byte) = u;
}

// --- pre-kernel: fp32 weights -> bf16 A-fragment order ----------------------
// lane l of frag (t,ks) holds W[t*16 + (l&15)][ks*32 + (l>>4)*8 + j], j=0..7
__global__ void pack_weights_kernel(const float* __restrict__ W1,
                                    const float* __restrict__ W2,
                                    const float* __restrict__ W3,
                                    __bf16* __restrict__ ws) {
    int t = blockIdx.x * blockDim.x + threadIdx.x;      // 0..16383
    const float* W; int K, KS, f, base;
    if (t < 4096)       { W = W1; K = 128; KS = 4; f = t;         base = WS_W1; }
    else if (t < 12288) { W = W2; K = 256; KS = 8; f = t - 4096;  base = WS_W2; }
    else                { W = W3; K = 256; KS = 8; f = t - 12288; base = WS_W3; }
    int lane = f & 63;
    int ks   = (f >> 6) % KS;
    int ct   = f / (64 * KS);
    int row  = ct * 16 + (lane & 15);
    int k0   = ks * 32 + (lane >> 4) * 8;
    const float* src = W + (size_t)row * K + k0;
    __bf16* dst = ws + base + (size_t)f * 8;
#pragma unroll
    for (int j = 0; j < 8; ++j) dst[j] = (__bf16)src[j];
}

// --- main fused kernel ------------------------------------------------------
__global__ __launch_bounds__(512, 3)
void embed_sim_kernel(const float* __restrict__ s1, const float* __restrict__ s2,
                      const float* __restrict__ b1, const float* __restrict__ b2,
                      const float* __restrict__ b3,
                      const __bf16* __restrict__ wf, float* __restrict__ out) {
    __shared__ __align__(16) __bf16 Xs[64 * 128];   // X,  then h2[:,  0:128]
    __shared__ __align__(16) __bf16 hA[64 * 128];   // h1[:,  0:128], then E
    __shared__ __align__(16) __bf16 hB[64 * 128];   // h1[:,128:256]
    __shared__ __align__(16) __bf16 hC[64 * 128];   // h2[:,128:256]

    const int tid  = threadIdx.x;
    const int wave = tid >> 6;        // 0..7
    const int lane = tid & 63;
    const int lr   = lane & 15;
    const int kg   = lane >> 4;
    const int p0   = blockIdx.x * 32;

    // ---- prefetch P1 weights (latency covered by X staging below) ----
    bf16x8 wfr1[2][4]; f32x4 bv1[2];
#pragma unroll
    for (int ti = 0; ti < 2; ++ti) {
        int t = wave * 2 + ti;
#pragma unroll
        for (int ks = 0; ks < 4; ++ks)
            wfr1[ti][ks] = *(const bf16x8*)(wf + WS_W1 + (size_t)((t * 4 + ks) * 64 + lane) * 8);
        bv1[ti] = *(const f32x4*)(b1 + t * 16 + kg * 4);
    }

    // ---- stage X: rows 0..31 = s1, rows 32..63 = s2 ----
#pragma unroll
    for (int it = 0; it < 2; ++it) {
        int idx = tid + it * 512;            // 0..1023
        int row = idx >> 4;
        int k0  = (idx & 15) << 3;
        const float* src = (row < 32) ? (s1 + (size_t)(p0 + row) * 128 + k0)
                                      : (s2 + (size_t)(p0 + row - 32) * 128 + k0);
        float4 v0 = *(const float4*)(src);
        float4 v1 = *(const float4*)(src + 4);
        bf16x8 w;
        w[0] = (__bf16)v0.x; w[1] = (__bf16)v0.y; w[2] = (__bf16)v0.z; w[3] = (__bf16)v0.w;
        w[4] = (__bf16)v1.x; w[5] = (__bf16)v1.y; w[6] = (__bf16)v1.z; w[7] = (__bf16)v1.w;
        unsigned byte = (unsigned)((row * 128 + k0) * 2) ^ ((unsigned)(row & 7) << 4);
        *(bf16x8*)((char*)Xs + byte) = w;
    }
    __syncthreads();

    // ---- prefetch P2 weights (latency covered by P1 compute) ----
    bf16x8 wfr2[2][8]; f32x4 bv2[2];
#pragma unroll
    for (int ti = 0; ti < 2; ++ti) {
        int t = wave * 2 + ti;
#pragma unroll
        for (int ks = 0; ks < 8; ++ks)
            wfr2[ti][ks] = *(const bf16x8*)(wf + WS_W2 + (size_t)((t * 8 + ks) * 64 + lane) * 8);
        bv2[ti] = *(const f32x4*)(b2 + t * 16 + kg * 4);
    }

    // ---- P1: L1 full (256 neurons; wave owns tiles 2w, 2w+1) Xs -> hA,hB ----
#pragma unroll
    for (int s = 0; s < 4; ++s) {
        bf16x8 xfr[4];
#pragma unroll
        for (int ks = 0; ks < 4; ++ks) xfr[ks] = read_act(Xs, s * 16 + lr, ks * 32 + kg * 8);
#pragma unroll
        for (int ti = 0; ti < 2; ++ti) {
            f32x4 acc = bv1[ti];
#pragma unroll
            for (int ks = 0; ks < 4; ++ks)
                acc = __builtin_amdgcn_mfma_f32_16x16x32_bf16(wfr1[ti][ks], xfr[ks], acc, 0, 0, 0);
            int t = wave * 2 + ti;
            store_act<true>((t < 8) ? hA : hB, s * 16 + lr, (t & 7) * 16 + kg * 4, acc);
        }
    }
    __syncthreads();

    // ---- prefetch P3 weights (latency covered by P2 compute) ----
    bf16x8 wfr3[8]; f32x4 bv3;
    {
        const int t = wave;
#pragma unroll
        for (int ks = 0; ks < 8; ++ks)
            wfr3[ks] = *(const bf16x8*)(wf + WS_W3 + (size_t)((t * 8 + ks) * 64 + lane) * 8);
        bv3 = *(const f32x4*)(b3 + t * 16 + kg * 4);
    }

    // ---- P2: L2 full-K (256) in ONE phase (wave owns tiles 2w,2w+1) ----
    //      hA,hB -> Xs (cols 0..127) / hC (cols 128..255)
#pragma unroll
    for (int s = 0; s < 4; ++s) {
        const int row = s * 16 + lr;
        bf16x8 hfr[8];
#pragma unroll
        for (int ks = 0; ks < 4; ++ks) {
            hfr[ks]     = read_act(hA, row, ks * 32 + kg * 8);
            hfr[4 + ks] = read_act(hB, row, ks * 32 + kg * 8);
        }
#pragma unroll
        for (int ti = 0; ti < 2; ++ti) {
            f32x4 acc = bv2[ti];
#pragma unroll
            for (int ks = 0; ks < 8; ++ks)
                acc = __builtin_amdgcn_mfma_f32_16x16x32_bf16(wfr2[ti][ks], hfr[ks], acc, 0, 0, 0);
            int t = wave * 2 + ti;
            store_act<true>((t < 8) ? Xs : hC, row, (t & 7) * 16 + kg * 4, acc);
        }
    }
    __syncthreads();

    // ---- P3: L3 (wave owns tile w of 8): Xs(k 0..127) + hC(k 128..255) -> hA ----
#pragma unroll
    for (int s = 0; s < 4; ++s) {
        const int row = s * 16 + lr;
        bf16x8 hfr[8];
#pragma unroll
        for (int ks = 0; ks < 4; ++ks) {
            hfr[ks]     = read_act(Xs, row, ks * 32 + kg * 8);
            hfr[4 + ks] = read_act(hC, row, ks * 32 + kg * 8);
        }
        f32x4 acc = bv3;
#pragma unroll
        for (int ks = 0; ks < 8; ++ks)
            acc = __builtin_amdgcn_mfma_f32_16x16x32_bf16(wfr3[ks], hfr[ks], acc, 0, 0, 0);
        store_act<false>(hA, row, wave * 16 + kg * 4, acc);
    }
    __syncthreads();

    // ---- epilogue: cosine similarity per pair (16 threads/pair), E in hA ----
    const int p  = tid >> 4;             // 0..31
    const int dg = tid & 15;
    const int d0 = dg * 8;
    float dot = 0.f, n1 = 0.f, n2 = 0.f;
    {
        unsigned by1 = (unsigned)((p * 128 + d0) * 2) ^ ((unsigned)(p & 7) << 4);
        unsigned by2 = (unsigned)(((p + 32) * 128 + d0) * 2) ^ ((unsigned)((p + 32) & 7) << 4);
        bf16x8 e1 = *(const bf16x8*)((const char*)hA + by1);
        bf16x8 e2 = *(const bf16x8*)((const char*)hA + by2);
#pragma unroll
        for (int j = 0; j < 8; ++j) {
            float a = (float)e1[j], b = (float)e2[j];
            dot = fmaf(a, b, dot);
            n1  = fmaf(a, a, n1);
            n2  = fmaf(b, b, n2);
        }
    }
#pragma unroll
    for (int off = 1; off < 16; off <<= 1) {
        dot += __shfl_xor(dot, off);
        n1  += __shfl_xor(n1,  off);
        n2  += __shfl_xor(n2,  off);
    }
    if (dg == 0) {
        float r = dot * rsqrtf(n1 * n2);
        float x = (r + 1.f) * 0.5f;
        out[p0 + p] = 1.f / (1.f + __expf(-x));
    }
}

// ---------------------------------------------------------------------------
extern "C" void kernel_launch(void* const* d_in, const int* in_sizes, int n_in,
                              void* d_out, int out_size, void* d_ws, size_t ws_size,
                              hipStream_t stream) {
    const float* s1 = (const float*)d_in[0];
    const float* s2 = (const float*)d_in[1];
    const float* W1 = (const float*)d_in[2];
    const float* b1 = (const float*)d_in[3];
    const float* W2 = (const float*)d_in[4];
    const float* b2 = (const float*)d_in[5];
    const float* W3 = (const float*)d_in[6];
    const float* b3 = (const float*)d_in[7];
    __bf16* wf = (__bf16*)d_ws;                 // 256 KiB of d_ws
    float*  outp = (float*)d_out;

    pack_weights_kernel<<<64, 256, 0, stream>>>(W1, W2, W3, wf);

    const int npairs = in_sizes[0] / 128;       // 65536
    embed_sim_kernel<<<npairs / 32, 512, 0, stream>>>(s1, s2, b1, b2, b3, wf, outp);
}

// Round 13
// 61.008 us; speedup vs baseline: 1.1075x; 1.1075x over previous
//
#include <hip/hip_runtime.h>

// ---------------------------------------------------------------------------
// Fused MLP-embedding cosine-similarity kernel for MI355X (gfx950).
//   e = (x @ W1^T + b1 -> selu) @ W2^T + b2 -> selu) @ W3^T + b3
//   out = sigmoid((cos(e1,e2)+1)/2)
// Round 13: identical to round 12 (infra failure — resubmitting).
// r8 structure (best: 58.8us) with LDS cut 64KB -> 48KB (3 buffers) ->
// 3 blocks/CU = 24 waves/CU (75% occupancy cap, was 50%).
// P2 accumulates full-K in regs (acc[2][4]=32 VGPR), writes h2-lo over dead
// X, barrier, waves 4-7 write h2-hi over hA (dead), barrier, P3 reads
// Xs+hA -> E into hB. r11 lesson: compiler sinks register prefetches —
// no source-level pipelining attempted; occupancy is the overlap lever.
// ---------------------------------------------------------------------------

typedef __bf16 bf16x8 __attribute__((ext_vector_type(8)));
typedef __bf16 bf16x4 __attribute__((ext_vector_type(4)));
typedef float  f32x4  __attribute__((ext_vector_type(4)));

constexpr int WS_W1 = 0;       // 16 tiles * 4 ks * 512 bf16
constexpr int WS_W2 = 32768;   // 16 tiles * 8 ks * 512
constexpr int WS_W3 = 98304;   //  8 tiles * 8 ks * 512

__device__ __forceinline__ float selu_f(float x) {
    const float scale = 1.0507009873554805f;
    const float sa    = 1.7580993408473766f;   // scale * alpha
    float xp = fmaxf(x, 0.f);
    float xn = fminf(x, 0.f);
    return fmaf(scale, xp, sa * (__expf(xn) - 1.f));
}

// activation fragment (B-operand): lane holds X[row][kcol .. kcol+7]
__device__ __forceinline__ bf16x8 read_act(const __bf16* lds, int row, int kcol) {
    unsigned byte = (unsigned)((row * 128 + kcol) * 2) ^ ((unsigned)(row & 7) << 4);
    return *(const bf16x8*)((const char*)lds + byte);
}

// store one D fragment: 4 consecutive neurons (col0..col0+3) at sample row
template<bool SELU>
__device__ __forceinline__ void store_act(__bf16* lds, int row, int col0, f32x4 a) {
    float v0 = a[0], v1 = a[1], v2 = a[2], v3 = a[3];
    if (SELU) { v0 = selu_f(v0); v1 = selu_f(v1); v2 = selu_f(v2); v3 = selu_f(v3); }
    bf16x4 u;
    u[0] = (__bf16)v0; u[1] = (__bf16)v1; u[2] = (__bf16)v2; u[3] = (__bf16)v3;
    unsigned byte = (unsigned)((row * 128 + col0) * 2) ^ ((unsigned)(row & 7) << 4);
    *(bf16x4*)((char*)lds + byte) = u;
}

// --- pre-kernel: fp32 weights -> bf16 A-fragment order ----------------------
// lane l of frag (t,ks) holds W[t*16 + (l&15)][ks*32 + (l>>4)*8 + j], j=0..7
__global__ void pack_weights_kernel(const float* __restrict__ W1,
                                    const float* __restrict__ W2,
                                    const float* __restrict__ W3,
                                    __bf16* __restrict__ ws) {
    int t = blockIdx.x * blockDim.x + threadIdx.x;      // 0..16383
    const float* W; int K, KS, f, base;
    if (t < 4096)       { W = W1; K = 128; KS = 4; f = t;         base = WS_W1; }
    else if (t < 12288) { W = W2; K = 256; KS = 8; f = t - 4096;  base = WS_W2; }
    else                { W = W3; K = 256; KS = 8; f = t - 12288; base = WS_W3; }
    int lane = f & 63;
    int ks   = (f >> 6) % KS;
    int ct   = f / (64 * KS);
    int row  = ct * 16 + (lane & 15);
    int k0   = ks * 32 + (lane >> 4) * 8;
    const float* src = W + (size_t)row * K + k0;
    __bf16* dst = ws + base + (size_t)f * 8;
#pragma unroll
    for (int j = 0; j < 8; ++j) dst[j] = (__bf16)src[j];
}

// --- main fused kernel ------------------------------------------------------
__global__ __launch_bounds__(512, 4)
void embed_sim_kernel(const float* __restrict__ s1, const float* __restrict__ s2,
                      const float* __restrict__ b1, const float* __restrict__ b2,
                      const float* __restrict__ b3,
                      const __bf16* __restrict__ wf, float* __restrict__ out) {
    __shared__ __align__(16) __bf16 Xs[64 * 128];   // X,        then h2[:,  0:128]
    __shared__ __align__(16) __bf16 hA[64 * 128];   // h1-lo,    then h2[:,128:256]
    __shared__ __align__(16) __bf16 hB[64 * 128];   // h1-hi,    then E

    const int tid  = threadIdx.x;
    const int wave = tid >> 6;        // 0..7
    const int lane = tid & 63;
    const int lr   = lane & 15;
    const int kg   = lane >> 4;
    const int p0   = blockIdx.x * 32;

    // ---- stage X: rows 0..31 = s1, rows 32..63 = s2 ----
#pragma unroll
    for (int it = 0; it < 2; ++it) {
        int idx = tid + it * 512;            // 0..1023
        int row = idx >> 4;
        int k0  = (idx & 15) << 3;
        const float* src = (row < 32) ? (s1 + (size_t)(p0 + row) * 128 + k0)
                                      : (s2 + (size_t)(p0 + row - 32) * 128 + k0);
        float4 v0 = *(const float4*)(src);
        float4 v1 = *(const float4*)(src + 4);
        bf16x8 w;
        w[0] = (__bf16)v0.x; w[1] = (__bf16)v0.y; w[2] = (__bf16)v0.z; w[3] = (__bf16)v0.w;
        w[4] = (__bf16)v1.x; w[5] = (__bf16)v1.y; w[6] = (__bf16)v1.z; w[7] = (__bf16)v1.w;
        unsigned byte = (unsigned)((row * 128 + k0) * 2) ^ ((unsigned)(row & 7) << 4);
        *(bf16x8*)((char*)Xs + byte) = w;
    }
    __syncthreads();

    // ---- P1: L1 full (256 neurons; wave owns tiles 2w, 2w+1) Xs -> hA,hB ----
    {
        bf16x8 wfr[2][4]; f32x4 bv[2];
#pragma unroll
        for (int ti = 0; ti < 2; ++ti) {
            int t = wave * 2 + ti;
#pragma unroll
            for (int ks = 0; ks < 4; ++ks)
                wfr[ti][ks] = *(const bf16x8*)(wf + WS_W1 + (size_t)((t * 4 + ks) * 64 + lane) * 8);
            bv[ti] = *(const f32x4*)(b1 + t * 16 + kg * 4);
        }
#pragma unroll
        for (int s = 0; s < 4; ++s) {
            bf16x8 xfr[4];
#pragma unroll
            for (int ks = 0; ks < 4; ++ks) xfr[ks] = read_act(Xs, s * 16 + lr, ks * 32 + kg * 8);
#pragma unroll
            for (int ti = 0; ti < 2; ++ti) {
                f32x4 acc = bv[ti];
#pragma unroll
                for (int ks = 0; ks < 4; ++ks)
                    acc = __builtin_amdgcn_mfma_f32_16x16x32_bf16(wfr[ti][ks], xfr[ks], acc, 0, 0, 0);
                int t = wave * 2 + ti;
                store_act<true>((t < 8) ? hA : hB, s * 16 + lr, (t & 7) * 16 + kg * 4, acc);
            }
        }
    }
    __syncthreads();

    // ---- P2: L2 full-K (256) in regs (wave owns tiles 2w,2w+1) ----
    //      reads hA (k 0..127) + hB (k 128..255); acc[2][4] = 32 VGPR
    {
        f32x4 acc[2][4];
        bf16x8 wfr[2][8];
#pragma unroll
        for (int ti = 0; ti < 2; ++ti) {
            int t = wave * 2 + ti;
#pragma unroll
            for (int ks = 0; ks < 8; ++ks)
                wfr[ti][ks] = *(const bf16x8*)(wf + WS_W2 + (size_t)((t * 8 + ks) * 64 + lane) * 8);
            f32x4 b = *(const f32x4*)(b2 + t * 16 + kg * 4);
#pragma unroll
            for (int s = 0; s < 4; ++s) acc[ti][s] = b;
        }
#pragma unroll
        for (int s = 0; s < 4; ++s) {
            const int row = s * 16 + lr;
            bf16x8 hfr[8];
#pragma unroll
            for (int ks = 0; ks < 4; ++ks) {
                hfr[ks]     = read_act(hA, row, ks * 32 + kg * 8);
                hfr[4 + ks] = read_act(hB, row, ks * 32 + kg * 8);
            }
#pragma unroll
            for (int ti = 0; ti < 2; ++ti)
#pragma unroll
                for (int ks = 0; ks < 8; ++ks)
                    acc[ti][s] = __builtin_amdgcn_mfma_f32_16x16x32_bf16(
                        wfr[ti][ks], hfr[ks], acc[ti][s], 0, 0, 0);
        }
        // h2-lo (tiles 0-7, waves 0-3) over dead X in Xs — safe pre-barrier
        if (wave < 4) {
#pragma unroll
            for (int ti = 0; ti < 2; ++ti)
#pragma unroll
                for (int s = 0; s < 4; ++s)
                    store_act<true>(Xs, s * 16 + lr, (wave * 2 + ti) * 16 + kg * 4, acc[ti][s]);
        }
        __syncthreads();
        // h2-hi (tiles 8-15, waves 4-7) over hA — dead after barrier
        if (wave >= 4) {
#pragma unroll
            for (int ti = 0; ti < 2; ++ti)
#pragma unroll
                for (int s = 0; s < 4; ++s)
                    store_act<true>(hA, s * 16 + lr, ((wave - 4) * 2 + ti) * 16 + kg * 4, acc[ti][s]);
        }
    }
    __syncthreads();

    // ---- P3: L3 (wave owns tile w of 8): Xs(k 0..127) + hA(k 128..255) -> hB ----
    {
        bf16x8 wfr[8]; f32x4 bv;
        const int t = wave;
#pragma unroll
        for (int ks = 0; ks < 8; ++ks)
            wfr[ks] = *(const bf16x8*)(wf + WS_W3 + (size_t)((t * 8 + ks) * 64 + lane) * 8);
        bv = *(const f32x4*)(b3 + t * 16 + kg * 4);
#pragma unroll
        for (int s = 0; s < 4; ++s) {
            const int row = s * 16 + lr;
            bf16x8 hfr[8];
#pragma unroll
            for (int ks = 0; ks < 4; ++ks) {
                hfr[ks]     = read_act(Xs, row, ks * 32 + kg * 8);
                hfr[4 + ks] = read_act(hA, row, ks * 32 + kg * 8);
            }
            f32x4 acc = bv;
#pragma unroll
            for (int ks = 0; ks < 8; ++ks)
                acc = __builtin_amdgcn_mfma_f32_16x16x32_bf16(wfr[ks], hfr[ks], acc, 0, 0, 0);
            store_act<false>(hB, row, t * 16 + kg * 4, acc);
        }
    }
    __syncthreads();

    // ---- epilogue: cosine similarity per pair (16 threads/pair), E in hB ----
    const int p  = tid >> 4;             // 0..31
    const int dg = tid & 15;
    const int d0 = dg * 8;
    float dot = 0.f, n1 = 0.f, n2 = 0.f;
    {
        unsigned by1 = (unsigned)((p * 128 + d0) * 2) ^ ((unsigned)(p & 7) << 4);
        unsigned by2 = (unsigned)(((p + 32) * 128 + d0) * 2) ^ ((unsigned)((p + 32) & 7) << 4);
        bf16x8 e1 = *(const bf16x8*)((const char*)hB + by1);
        bf16x8 e2 = *(const bf16x8*)((const char*)hB + by2);
#pragma unroll
        for (int j = 0; j < 8; ++j) {
            float a = (float)e1[j], b = (float)e2[j];
            dot = fmaf(a, b, dot);
            n1  = fmaf(a, a, n1);
            n2  = fmaf(b, b, n2);
        }
    }
#pragma unroll
    for (int off = 1; off < 16; off <<= 1) {
        dot += __shfl_xor(dot, off);
        n1  += __shfl_xor(n1,  off);
        n2  += __shfl_xor(n2,  off);
    }
    if (dg == 0) {
        float r = dot * rsqrtf(n1 * n2);
        float x = (r + 1.f) * 0.5f;
        out[p0 + p] = 1.f / (1.f + __expf(-x));
    }
}

// ---------------------------------------------------------------------------
extern "C" void kernel_launch(void* const* d_in, const int* in_sizes, int n_in,
                              void* d_out, int out_size, void* d_ws, size_t ws_size,
                              hipStream_t stream) {
    const float* s1 = (const float*)d_in[0];
    const float* s2 = (const float*)d_in[1];
    const float* W1 = (const float*)d_in[2];
    const float* b1 = (const float*)d_in[3];
    const float* W2 = (const float*)d_in[4];
    const float* b2 = (const float*)d_in[5];
    const float* W3 = (const float*)d_in[6];
    const float* b3 = (const float*)d_in[7];
    __bf16* wf = (__bf16*)d_ws;                 // 256 KiB of d_ws
    float*  outp = (float*)d_out;

    pack_weights_kernel<<<64, 256, 0, stream>>>(W1, W2, W3, wf);

    const int npairs = in_sizes[0] / 128;       // 65536
    embed_sim_kernel<<<npairs / 32, 512, 0, stream>>>(s1, s2, b1, b2, b3, wf, outp);
}

// Round 14
// 58.221 us; speedup vs baseline: 1.1606x; 1.0479x over previous
//
#include <hip/hip_runtime.h>

// ---------------------------------------------------------------------------
// Fused MLP-embedding cosine-similarity kernel for MI355X (gfx950).
//   e = (x @ W1^T + b1 -> selu) @ W2^T + b2 -> selu) @ W3^T + b3
//   out = sigmoid((cos(e1,e2)+1)/2)
// Round 14: LDS-throughput-bound (r13 proved occupancy cap non-binding:
// raised 50->75% cap, measured stayed 38%). Halve activation LDS reads by
// doubling cols-per-wave: 4 waves x (64 cols x 64 rows) instead of
// 8 x (32 x 64). Act reads 640->320 KB/block; weight L2 stays minimal
// (256 KB/block, no duplication — the r9/r10 mistake). P2: acc[4][4]=64
// VGPR + K-half weight batches (64 VGPR) ~150 peak -> launch_bounds(256,3)
// (170 cap; 3 blocks/CU = 12 waves/CU matches 48KB LDS cap).
// LDS: Xs[64][128] (X -> h2-lo), hA[64][256] (h1 -> {h2-hi, E}).
// ---------------------------------------------------------------------------

typedef __bf16 bf16x8 __attribute__((ext_vector_type(8)));
typedef __bf16 bf16x4 __attribute__((ext_vector_type(4)));
typedef float  f32x4  __attribute__((ext_vector_type(4)));

constexpr int WS_W1 = 0;       // 16 tiles * 4 ks * 512 bf16
constexpr int WS_W2 = 32768;   // 16 tiles * 8 ks * 512
constexpr int WS_W3 = 98304;   //  8 tiles * 8 ks * 512

__device__ __forceinline__ float selu_f(float x) {
    const float scale = 1.0507009873554805f;
    const float sa    = 1.7580993408473766f;   // scale * alpha
    float xp = fmaxf(x, 0.f);
    float xn = fminf(x, 0.f);
    return fmaf(scale, xp, sa * (__expf(xn) - 1.f));
}

// activation fragment (B-operand): lane holds X[row][kcol .. kcol+7]
template<int COLS>
__device__ __forceinline__ bf16x8 read_act(const __bf16* lds, int row, int kcol) {
    unsigned byte = (unsigned)((row * COLS + kcol) * 2) ^ ((unsigned)(row & 7) << 4);
    return *(const bf16x8*)((const char*)lds + byte);
}

// store one D fragment: 4 consecutive neurons (col0..col0+3) at sample row
template<bool SELU, int COLS>
__device__ __forceinline__ void store_act(__bf16* lds, int row, int col0, f32x4 a) {
    float v0 = a[0], v1 = a[1], v2 = a[2], v3 = a[3];
    if (SELU) { v0 = selu_f(v0); v1 = selu_f(v1); v2 = selu_f(v2); v3 = selu_f(v3); }
    bf16x4 u;
    u[0] = (__bf16)v0; u[1] = (__bf16)v1; u[2] = (__bf16)v2; u[3] = (__bf16)v3;
    unsigned byte = (unsigned)((row * COLS + col0) * 2) ^ ((unsigned)(row & 7) << 4);
    *(bf16x4*)((char*)lds + byte) = u;
}

// --- pre-kernel: fp32 weights -> bf16 A-fragment order ----------------------
// lane l of frag (t,ks) holds W[t*16 + (l&15)][ks*32 + (l>>4)*8 + j], j=0..7
__global__ void pack_weights_kernel(const float* __restrict__ W1,
                                    const float* __restrict__ W2,
                                    const float* __restrict__ W3,
                                    __bf16* __restrict__ ws) {
    int t = blockIdx.x * blockDim.x + threadIdx.x;      // 0..16383
    const float* W; int K, KS, f, base;
    if (t < 4096)       { W = W1; K = 128; KS = 4; f = t;         base = WS_W1; }
    else if (t < 12288) { W = W2; K = 256; KS = 8; f = t - 4096;  base = WS_W2; }
    else                { W = W3; K = 256; KS = 8; f = t - 12288; base = WS_W3; }
    int lane = f & 63;
    int ks   = (f >> 6) % KS;
    int ct   = f / (64 * KS);
    int row  = ct * 16 + (lane & 15);
    int k0   = ks * 32 + (lane >> 4) * 8;
    const float* src = W + (size_t)row * K + k0;
    __bf16* dst = ws + base + (size_t)f * 8;
#pragma unroll
    for (int j = 0; j < 8; ++j) dst[j] = (__bf16)src[j];
}

// --- main fused kernel ------------------------------------------------------
// 4 waves x 64 rows; wave owns 64 output cols (4 ntiles) in 256-col layers,
// 32 cols (2 ntiles) in the 128-col layer.
__global__ __launch_bounds__(256, 3)
void embed_sim_kernel(const float* __restrict__ s1, const float* __restrict__ s2,
                      const float* __restrict__ b1, const float* __restrict__ b2,
                      const float* __restrict__ b3,
                      const __bf16* __restrict__ wf, float* __restrict__ out) {
    __shared__ __align__(16) __bf16 Xs[64 * 128];   // X, later h2[:,0:128]
    __shared__ __align__(16) __bf16 hA[64 * 256];   // h1; later h2[:,128:256] (front 16K) + E (back 16K)

    const int tid  = threadIdx.x;
    const int wave = tid >> 6;        // 0..3
    const int lane = tid & 63;
    const int lr   = lane & 15;
    const int kg   = lane >> 4;
    const int p0   = blockIdx.x * 32;

    __bf16* h2hi = hA;                // [64][128] after h1 is dead
    __bf16* Es   = hA + 64 * 128;     // [64][128]

    // ---- stage X: rows 0..31 = s1, rows 32..63 = s2 ----
#pragma unroll
    for (int it = 0; it < 4; ++it) {
        int idx = tid + it * 256;            // 0..1023
        int row = idx >> 4;
        int k0  = (idx & 15) << 3;
        const float* src = (row < 32) ? (s1 + (size_t)(p0 + row) * 128 + k0)
                                      : (s2 + (size_t)(p0 + row - 32) * 128 + k0);
        float4 v0 = *(const float4*)(src);
        float4 v1 = *(const float4*)(src + 4);
        bf16x8 w;
        w[0] = (__bf16)v0.x; w[1] = (__bf16)v0.y; w[2] = (__bf16)v0.z; w[3] = (__bf16)v0.w;
        w[4] = (__bf16)v1.x; w[5] = (__bf16)v1.y; w[6] = (__bf16)v1.z; w[7] = (__bf16)v1.w;
        unsigned byte = (unsigned)((row * 128 + k0) * 2) ^ ((unsigned)(row & 7) << 4);
        *(bf16x8*)((char*)Xs + byte) = w;
    }
    __syncthreads();

    // ---- P1: L1 (256 out; wave owns ntiles 4w..4w+3) Xs -> hA[64][256] ----
    {
        bf16x8 wfr[4][4]; f32x4 bv[4];
#pragma unroll
        for (int ti = 0; ti < 4; ++ti) {
            int t = wave * 4 + ti;
#pragma unroll
            for (int ks = 0; ks < 4; ++ks)
                wfr[ti][ks] = *(const bf16x8*)(wf + WS_W1 + (size_t)((t * 4 + ks) * 64 + lane) * 8);
            bv[ti] = *(const f32x4*)(b1 + t * 16 + kg * 4);
        }
#pragma unroll
        for (int s = 0; s < 4; ++s) {
            const int row = s * 16 + lr;
            bf16x8 xfr[4];
#pragma unroll
            for (int ks = 0; ks < 4; ++ks) xfr[ks] = read_act<128>(Xs, row, ks * 32 + kg * 8);
#pragma unroll
            for (int ti = 0; ti < 4; ++ti) {
                f32x4 acc = bv[ti];
#pragma unroll
                for (int ks = 0; ks < 4; ++ks)
                    acc = __builtin_amdgcn_mfma_f32_16x16x32_bf16(wfr[ti][ks], xfr[ks], acc, 0, 0, 0);
                store_act<true, 256>(hA, row, (wave * 4 + ti) * 16 + kg * 4, acc);
            }
        }
    }
    __syncthreads();

    // ---- P2: L2 full-K in regs (wave owns ntiles 4w..4w+3, all 4 stripes) ----
    {
        f32x4 acc[4][4];                  // [ti][stripe] = 64 VGPR
#pragma unroll
        for (int ti = 0; ti < 4; ++ti) {
            f32x4 b = *(const f32x4*)(b2 + (wave * 4 + ti) * 16 + kg * 4);
#pragma unroll
            for (int s = 0; s < 4; ++s) acc[ti][s] = b;
        }
#pragma unroll
        for (int kh = 0; kh < 2; ++kh) {  // two K-halves; weights 64 VGPR each
            bf16x8 wfr[4][4];
#pragma unroll
            for (int ti = 0; ti < 4; ++ti) {
                int t = wave * 4 + ti;
#pragma unroll
                for (int ks = 0; ks < 4; ++ks)
                    wfr[ti][ks] = *(const bf16x8*)(wf + WS_W2 + (size_t)((t * 8 + kh * 4 + ks) * 64 + lane) * 8);
            }
#pragma unroll
            for (int s = 0; s < 4; ++s) {
                const int row = s * 16 + lr;
                bf16x8 hfr[4];
#pragma unroll
                for (int ks = 0; ks < 4; ++ks)
                    hfr[ks] = read_act<256>(hA, row, kh * 128 + ks * 32 + kg * 8);
#pragma unroll
                for (int ti = 0; ti < 4; ++ti)
#pragma unroll
                    for (int ks = 0; ks < 4; ++ks)
                        acc[ti][s] = __builtin_amdgcn_mfma_f32_16x16x32_bf16(
                            wfr[ti][ks], hfr[ks], acc[ti][s], 0, 0, 0);
            }
        }
        // h2-lo (waves 0,1 -> cols 0..127) over dead X — safe pre-barrier
        if (wave < 2) {
#pragma unroll
            for (int ti = 0; ti < 4; ++ti)
#pragma unroll
                for (int s = 0; s < 4; ++s)
                    store_act<true, 128>(Xs, s * 16 + lr, (wave * 4 + ti) * 16 + kg * 4, acc[ti][s]);
        }
        __syncthreads();                  // all hA (h1) reads complete
        // h2-hi (waves 2,3 -> cols 128..255) over hA front — h1 dead now
        if (wave >= 2) {
#pragma unroll
            for (int ti = 0; ti < 4; ++ti)
#pragma unroll
                for (int s = 0; s < 4; ++s)
                    store_act<true, 128>(h2hi, s * 16 + lr, ((wave - 2) * 4 + ti) * 16 + kg * 4, acc[ti][s]);
        }
    }
    __syncthreads();

    // ---- P3: L3 (128 out; wave owns ntiles 2w,2w+1): Xs + h2hi -> Es ----
    {
        f32x4 acc[2][4];
#pragma unroll
        for (int ti = 0; ti < 2; ++ti) {
            f32x4 b = *(const f32x4*)(b3 + (wave * 2 + ti) * 16 + kg * 4);
#pragma unroll
            for (int s = 0; s < 4; ++s) acc[ti][s] = b;
        }
#pragma unroll
        for (int kh = 0; kh < 2; ++kh) {
            const __bf16* src = (kh == 0) ? Xs : h2hi;
            bf16x8 wfr[2][4];
#pragma unroll
            for (int ti = 0; ti < 2; ++ti) {
                int t = wave * 2 + ti;
#pragma unroll
                for (int ks = 0; ks < 4; ++ks)
                    wfr[ti][ks] = *(const bf16x8*)(wf + WS_W3 + (size_t)((t * 8 + kh * 4 + ks) * 64 + lane) * 8);
            }
#pragma unroll
            for (int s = 0; s < 4; ++s) {
                const int row = s * 16 + lr;
                bf16x8 hfr[4];
#pragma unroll
                for (int ks = 0; ks < 4; ++ks)
                    hfr[ks] = read_act<128>(src, row, ks * 32 + kg * 8);
#pragma unroll
                for (int ti = 0; ti < 2; ++ti)
#pragma unroll
                    for (int ks = 0; ks < 4; ++ks)
                        acc[ti][s] = __builtin_amdgcn_mfma_f32_16x16x32_bf16(
                            wfr[ti][ks], hfr[ks], acc[ti][s], 0, 0, 0);
            }
        }
#pragma unroll
        for (int ti = 0; ti < 2; ++ti)
#pragma unroll
            for (int s = 0; s < 4; ++s)
                store_act<false, 128>(Es, s * 16 + lr, (wave * 2 + ti) * 16 + kg * 4, acc[ti][s]);
    }
    __syncthreads();

    // ---- epilogue: cosine similarity per pair (8 threads/pair), E in Es ----
    const int p  = tid >> 3;             // 0..31
    const int dg = tid & 7;
    float dot = 0.f, n1 = 0.f, n2 = 0.f;
#pragma unroll
    for (int half = 0; half < 2; ++half) {
        int d0 = dg * 16 + half * 8;
        unsigned by1 = (unsigned)((p * 128 + d0) * 2) ^ ((unsigned)(p & 7) << 4);
        unsigned by2 = (unsigned)(((p + 32) * 128 + d0) * 2) ^ ((unsigned)((p + 32) & 7) << 4);
        bf16x8 e1 = *(const bf16x8*)((const char*)Es + by1);
        bf16x8 e2 = *(const bf16x8*)((const char*)Es + by2);
#pragma unroll
        for (int j = 0; j < 8; ++j) {
            float a = (float)e1[j], b = (float)e2[j];
            dot = fmaf(a, b, dot);
            n1  = fmaf(a, a, n1);
            n2  = fmaf(b, b, n2);
        }
    }
#pragma unroll
    for (int off = 1; off < 8; off <<= 1) {
        dot += __shfl_xor(dot, off);
        n1  += __shfl_xor(n1,  off);
        n2  += __shfl_xor(n2,  off);
    }
    if (dg == 0) {
        float r = dot * rsqrtf(n1 * n2);
        float x = (r + 1.f) * 0.5f;
        out[p0 + p] = 1.f / (1.f + __expf(-x));
    }
}

// ---------------------------------------------------------------------------
extern "C" void kernel_launch(void* const* d_in, const int* in_sizes, int n_in,
                              void* d_out, int out_size, void* d_ws, size_t ws_size,
                              hipStream_t stream) {
    const float* s1 = (const float*)d_in[0];
    const float* s2 = (const float*)d_in[1];
    const float* W1 = (const float*)d_in[2];
    const float* b1 = (const float*)d_in[3];
    const float* W2 = (const float*)d_in[4];
    const float* b2 = (const float*)d_in[5];
    const float* W3 = (const float*)d_in[6];
    const float* b3 = (const float*)d_in[7];
    __bf16* wf = (__bf16*)d_ws;                 // 256 KiB of d_ws
    float*  outp = (float*)d_out;

    pack_weights_kernel<<<64, 256, 0, stream>>>(W1, W2, W3, wf);

    const int npairs = in_sizes[0] / 128;       // 65536
    embed_sim_kernel<<<npairs / 32, 256, 0, stream>>>(s1, s2, b1, b2, b3, wf, outp);
}